// Round 1
// baseline (1847.486 us; speedup 1.0000x reference)
//
#include <hip/hip_runtime.h>
#include <algorithm>
#include <stdint.h>

// Problem constants (fixed by reference)
#define NB 32
#define NH 8
#define NE 64
#define NO 64
#define NM 64
#define NL 2048

struct Idx128 { int q[64]; int kv[64]; };

// ---- workspace layout (float offsets) ----
#define OFF_FQ    0          // [t][m] float2      : 131072 float2
#define OFF_FKV   262144     // [t][m] float2
#define OFF_BAS   524288     // [p][m][l] float    : 2*64*2048
#define OFF_WT    786432     // [h][x][e][o] float2: 2097152 float2
#define OFF_XQ    4980736    // [b][h][m][e] float2
#define OFF_XK    7077888    // [b][h][m][e] float2
#define OFF_SC    9175040    // [b][h][x][y] float2
#define OFF_XQKV  11272192   // [h][x][b][e] float2
#define OFF_XW    13369344   // [b][h][m][p][o] float
// total 15,466,496 floats = 61.9 MB

#define DPI 3.14159265358979323846

// ============ host-side replication of numpy legacy RNG ============
namespace fca_mt {
struct MT {
  uint32_t mt[624]; int mti;
  void seed(uint32_t s){
    mt[0]=s;
    for(int i=1;i<624;i++) mt[i]=1812433253u*(mt[i-1]^(mt[i-1]>>30))+(uint32_t)i;
    mti=624;
  }
  uint32_t next(){
    if(mti>=624){
      for(int i=0;i<624;i++){
        uint32_t y=(mt[i]&0x80000000u)|(mt[(i+1)%624]&0x7fffffffu);
        uint32_t v=mt[(i+397)%624]^(y>>1);
        if(y&1u) v^=0x9908b0dfu;
        mt[i]=v;
      }
      mti=0;
    }
    uint32_t y=mt[mti++];
    y^=y>>11; y^=(y<<7)&0x9d2c5680u; y^=(y<<15)&0xefc60000u; y^=y>>18;
    return y;
  }
  uint32_t interval(uint32_t mx){   // numpy random_interval: masked rejection
    if(mx==0) return 0;
    uint32_t mask=mx;
    mask|=mask>>1; mask|=mask>>2; mask|=mask>>4; mask|=mask>>8; mask|=mask>>16;
    uint32_t v;
    do { v = next()&mask; } while(v>mx);
    return v;
  }
};
} // namespace

// ============ table generation (double trig for exact twiddles) ============
__global__ __launch_bounds__(256) void fca_tables(float* __restrict__ ws, Idx128 idx){
  int i = blockIdx.x*256 + threadIdx.x;
  if(i < 131072){                       // FQ[t][m] = e^{-2pi i f t / L}
    int t = i>>6, m = i&63;
    int f = idx.q[m];
    int r = (f*t) & 2047;
    double th = 2.0*DPI*(double)r/2048.0;
    ((float2*)(ws+OFF_FQ))[i] = make_float2((float)cos(th), (float)(-sin(th)));
  } else if(i < 262144){                // FKV[t][m]
    int j = i-131072;
    int t = j>>6, m = j&63;
    int f = idx.kv[m];
    int r = (f*t) & 2047;
    double th = 2.0*DPI*(double)r/2048.0;
    ((float2*)(ws+OFF_FKV))[j] = make_float2((float)cos(th), (float)(-sin(th)));
  } else if(i < 393216){                // BAS: BC[m][l], BS[m][l]
    int j = i-262144;
    int m = j>>11, l = j&2047;
    int f = idx.q[m];
    int r = (f*l) & 2047;
    double th = 2.0*DPI*(double)r/2048.0;
    double a = ((f==0)?1.0:2.0)/(2048.0*262144.0);  // irfft 1/n + /(IC*OC), x2 for hermitian pair
    float* bas = ws+OFF_BAS;
    bas[j]          = (float)( a*cos(th));
    bas[131072 + j] = (float)(-a*sin(th));
  }
}

// transpose weights: w[h][e][o][x] -> wt[h][x][e][o] (float2 = re,im)
__global__ __launch_bounds__(256) void fca_wt(const float* __restrict__ wr, const float* __restrict__ wi,
                                              float2* __restrict__ wt){
  int i = blockIdx.x*256 + threadIdx.x;   // < 2097152
  int x = i&63, o = (i>>6)&63, e = (i>>12)&63, h = i>>18;
  wt[ (((size_t)(h*64+x)*64+e)*64) + o ] = make_float2(wr[i], wi[i]);
}

// sparse-mode DFT over t (K=2048): X[b][h][m][e] for q (z=0) and k (z=1)
__global__ __launch_bounds__(256) void fca_dft(const float* __restrict__ qg, const float* __restrict__ kg,
                                               float* __restrict__ ws){
  const int b   = blockIdx.x;   // 32
  const int heq = blockIdx.y;   // 4 : he-quarter (128 channels)
  const int isK = blockIdx.z;   // 2
  const float* src = isK ? kg : qg;
  const float2* tab = (const float2*)(ws + (isK ? OFF_FKV : OFF_FQ));
  float2* dst = (float2*)(ws + (isK ? OFF_XK : OFF_XQ));

  __shared__ float  lq[32][128];
  __shared__ float2 lt[32][64];

  const int tid = threadIdx.x;
  const int hg = tid & 31;        // he-group: 4 consecutive channels
  const int mg = tid >> 5;        // 8 groups x 8 modes
  const int he0 = hg*4;
  const int m0 = mg*8;

  float accr[4][8], acci[4][8];
  #pragma unroll
  for(int j=0;j<4;j++){
    #pragma unroll
    for(int mm=0;mm<8;mm++){ accr[j][mm]=0.f; acci[j][mm]=0.f; }
  }

  for(int t0=0;t0<2048;t0+=32){
    #pragma unroll
    for(int kk=0;kk<16;kk++){
      int el = kk*256 + tid;
      int tt = el>>7, he = el&127;
      lq[tt][he] = src[ (size_t)(b*2048 + t0+tt)*512 + heq*128 + he ];
    }
    #pragma unroll
    for(int kk=0;kk<8;kk++){
      int el = kk*256 + tid;
      int tt = el>>6, m = el&63;
      lt[tt][m] = tab[(t0+tt)*64 + m];
    }
    __syncthreads();
    #pragma unroll 4
    for(int tt=0;tt<32;tt++){
      const float4 qa = *(const float4*)&lq[tt][he0];
      #pragma unroll
      for(int mm=0;mm<8;mm++){
        const float2 f = lt[tt][m0+mm];
        accr[0][mm] += qa.x*f.x; acci[0][mm] += qa.x*f.y;
        accr[1][mm] += qa.y*f.x; acci[1][mm] += qa.y*f.y;
        accr[2][mm] += qa.z*f.x; acci[2][mm] += qa.z*f.y;
        accr[3][mm] += qa.w*f.x; acci[3][mm] += qa.w*f.y;
      }
    }
    __syncthreads();
  }
  #pragma unroll
  for(int j=0;j<4;j++){
    int he = heq*128 + he0 + j;
    int h = he>>6, e = he&63;
    #pragma unroll
    for(int mm=0;mm<8;mm++){
      dst[ ((size_t)(b*8+h)*64 + (m0+mm))*64 + e ] = make_float2(accr[j][mm], acci[j][mm]);
    }
  }
}

__device__ __forceinline__ float2 fca_ctanh(float2 z){
  float tx = tanhf(z.x);
  float ty = tanf(z.y);
  float tx2 = tx*tx, ty2 = ty*ty;
  // tanh(x+iy) = (tx(1+ty^2) + i ty(1-tx^2)) / (1 + tx^2 ty^2)
  float d = 1.0f + tx2*ty2;
  return make_float2( tx*(1.0f+ty2)/d, ty*(1.0f-tx2)/d );
}

// scores[b][h][x][y] = tanh( sum_e xq[x][e]*xk[y][e] )   (complex, no conj)
__global__ __launch_bounds__(256) void fca_scores(float* __restrict__ ws){
  const int b = blockIdx.x, h = blockIdx.y;
  __shared__ float2 lxq[64][64];   // [x][e]
  __shared__ float2 lxk[64][65];   // [e][y] transposed, padded
  const int tid = threadIdx.x;
  const float2* srcq = (const float2*)(ws+OFF_XQ) + (size_t)(b*8+h)*4096;
  const float2* srck = (const float2*)(ws+OFF_XK) + (size_t)(b*8+h)*4096;
  #pragma unroll
  for(int kk=0;kk<16;kk++){
    int el = kk*256 + tid;
    ((float2*)lxq)[el] = srcq[el];
  }
  #pragma unroll
  for(int kk=0;kk<16;kk++){
    int el = kk*256 + tid;
    int y = el>>6, e = el&63;
    lxk[e][y] = srck[el];
  }
  __syncthreads();
  const int y = tid&63, xg = tid>>6;
  float2 acc[16];
  #pragma unroll
  for(int i=0;i<16;i++) acc[i]=make_float2(0.f,0.f);
  for(int e=0;e<64;e++){
    const float2 kv = lxk[e][y];
    #pragma unroll
    for(int i=0;i<16;i++){
      const float2 qv = lxq[xg*16+i][e];
      acc[i].x += qv.x*kv.x - qv.y*kv.y;
      acc[i].y += qv.x*kv.y + qv.y*kv.x;
    }
  }
  float2* outp = (float2*)(ws+OFF_SC) + (size_t)(b*8+h)*4096;
  #pragma unroll
  for(int i=0;i<16;i++){
    outp[(xg*16+i)*64 + y] = fca_ctanh(acc[i]);
  }
}

// xqkv[h][x][b][e] = sum_y scores[x][y] * xk[y][e]
__global__ __launch_bounds__(256) void fca_pv(float* __restrict__ ws){
  const int b = blockIdx.x, h = blockIdx.y;
  __shared__ float2 ls[64][64];   // [x][y]
  __shared__ float2 lk[64][64];   // [y][e]
  const int tid = threadIdx.x;
  const float2* srcs = (const float2*)(ws+OFF_SC) + (size_t)(b*8+h)*4096;
  const float2* srck = (const float2*)(ws+OFF_XK) + (size_t)(b*8+h)*4096;
  #pragma unroll
  for(int kk=0;kk<16;kk++){
    int el=kk*256+tid;
    ((float2*)ls)[el]=srcs[el];
    ((float2*)lk)[el]=srck[el];
  }
  __syncthreads();
  const int e = tid&63, xg = tid>>6;
  float2 acc[16];
  #pragma unroll
  for(int i=0;i<16;i++) acc[i]=make_float2(0.f,0.f);
  for(int y=0;y<64;y++){
    const float2 kv = lk[y][e];
    #pragma unroll
    for(int i=0;i<16;i++){
      const float2 s = ls[xg*16+i][y];
      acc[i].x += s.x*kv.x - s.y*kv.y;
      acc[i].y += s.x*kv.y + s.y*kv.x;
    }
  }
  float2* dst = (float2*)(ws+OFF_XQKV);
  #pragma unroll
  for(int i=0;i<16;i++){
    int x = xg*16+i;
    dst[ ((size_t)(h*64+x)*32 + b)*64 + e ] = acc[i];
  }
}

// xw[b][h][x][p][o] = sum_e xqkv[h][x][b][e] * wt[h][x][e][o]   (complex -> re/im planes)
__global__ __launch_bounds__(256) void fca_ow(float* __restrict__ ws){
  const int h = blockIdx.x, x = blockIdx.y;
  __shared__ float2 lw[64][64];  // [e][o]
  __shared__ float2 lx[32][64];  // [b][e]
  const int tid = threadIdx.x;
  const float2* srcw = (const float2*)(ws+OFF_WT)   + (size_t)(h*64+x)*4096;
  const float2* srcx = (const float2*)(ws+OFF_XQKV) + (size_t)(h*64+x)*2048;
  #pragma unroll
  for(int kk=0;kk<16;kk++){ int el=kk*256+tid; ((float2*)lw)[el]=srcw[el]; }
  #pragma unroll
  for(int kk=0;kk<8;kk++){ int el=kk*256+tid; ((float2*)lx)[el]=srcx[el]; }
  __syncthreads();
  const int o = tid&63, bg = tid>>6;
  float2 acc[8];
  #pragma unroll
  for(int i=0;i<8;i++) acc[i]=make_float2(0.f,0.f);
  for(int e=0;e<64;e++){
    const float2 wv = lw[e][o];
    #pragma unroll
    for(int i=0;i<8;i++){
      const float2 xv = lx[bg*8+i][e];
      acc[i].x += xv.x*wv.x - xv.y*wv.y;
      acc[i].y += xv.x*wv.y + xv.y*wv.x;
    }
  }
  float* xw = ws+OFF_XW;
  #pragma unroll
  for(int i=0;i<8;i++){
    int b = bg*8+i;
    size_t base = ((size_t)((b*8+h)*64 + x))*128;
    xw[base + o]      = acc[i].x;
    xw[base + 64 + o] = acc[i].y;
  }
}

// out[b][h][o][l] = sum_m ReX[m][o]*BC[m][l] + ImX[m][o]*BS[m][l]
__global__ __launch_bounds__(256) void fca_irfft(const float* __restrict__ ws, float* __restrict__ outg){
  const int b = blockIdx.x, h = blockIdx.y, lc = blockIdx.z; // lc: 8 chunks of 256 l
  __shared__ float lX[64][2][64];
  __shared__ float lB[16][2][256];
  const int tid = threadIdx.x;
  const float* xw = ws+OFF_XW + (size_t)(b*8+h)*8192;
  #pragma unroll
  for(int kk=0;kk<8;kk++){
    int el = kk*256+tid;
    ((float4*)lX)[el] = ((const float4*)xw)[el];
  }
  const int li = tid&63, og = tid>>6;
  float4 acc4[16];
  #pragma unroll
  for(int i=0;i<16;i++) acc4[i]=make_float4(0.f,0.f,0.f,0.f);
  const float* bas = ws+OFF_BAS;
  for(int mc=0;mc<4;mc++){
    __syncthreads();
    #pragma unroll
    for(int kk=0;kk<32;kk++){
      int el = kk*256+tid;
      int m = el>>9, p = (el>>8)&1, l = el&255;
      lB[m][p][l] = bas[p*131072 + (mc*16+m)*2048 + lc*256 + l];
    }
    __syncthreads();
    #pragma unroll
    for(int m=0;m<16;m++){
      const int gm = mc*16+m;
      const float4 bc = *(const float4*)&lB[m][0][li*4];
      const float4 bs = *(const float4*)&lB[m][1][li*4];
      #pragma unroll
      for(int i2=0;i2<4;i2++){
        const float4 xr = *(const float4*)&lX[gm][0][og*16+i2*4];
        const float4 xi = *(const float4*)&lX[gm][1][og*16+i2*4];
        acc4[i2*4+0].x += xr.x*bc.x + xi.x*bs.x;
        acc4[i2*4+0].y += xr.x*bc.y + xi.x*bs.y;
        acc4[i2*4+0].z += xr.x*bc.z + xi.x*bs.z;
        acc4[i2*4+0].w += xr.x*bc.w + xi.x*bs.w;
        acc4[i2*4+1].x += xr.y*bc.x + xi.y*bs.x;
        acc4[i2*4+1].y += xr.y*bc.y + xi.y*bs.y;
        acc4[i2*4+1].z += xr.y*bc.z + xi.y*bs.z;
        acc4[i2*4+1].w += xr.y*bc.w + xi.y*bs.w;
        acc4[i2*4+2].x += xr.z*bc.x + xi.z*bs.x;
        acc4[i2*4+2].y += xr.z*bc.y + xi.z*bs.y;
        acc4[i2*4+2].z += xr.z*bc.z + xi.z*bs.z;
        acc4[i2*4+2].w += xr.z*bc.w + xi.z*bs.w;
        acc4[i2*4+3].x += xr.w*bc.x + xi.w*bs.x;
        acc4[i2*4+3].y += xr.w*bc.y + xi.w*bs.y;
        acc4[i2*4+3].z += xr.w*bc.z + xi.w*bs.z;
        acc4[i2*4+3].w += xr.w*bc.w + xi.w*bs.w;
      }
    }
  }
  #pragma unroll
  for(int i=0;i<16;i++){
    int o = og*16+i;
    *(float4*)&outg[ ((size_t)(b*8+h)*64 + o)*2048 + lc*256 + li*4 ] = acc4[i];
  }
}

extern "C" void kernel_launch(void* const* d_in, const int* in_sizes, int n_in,
                              void* d_out, int out_size, void* d_ws, size_t ws_size,
                              hipStream_t stream) {
  (void)in_sizes; (void)n_in; (void)out_size; (void)ws_size;
  const float* q  = (const float*)d_in[0];
  const float* k  = (const float*)d_in[1];
  const float* wr = (const float*)d_in[4];
  const float* wi = (const float*)d_in[5];
  float* out = (float*)d_out;
  float* ws  = (float*)d_ws;

  // Replicate the reference's module-level mode selection exactly
  // (np.random.seed(0); shuffle(arange(1024)) twice, first 64 sorted each).
  Idx128 idx;
  {
    fca_mt::MT rng; rng.seed(0u);
    int tmp[1024];
    for(int pass=0; pass<2; pass++){
      for(int i=0;i<1024;i++) tmp[i]=i;
      for(int i=1023;i>0;i--){
        int j = (int)rng.interval((uint32_t)i);
        int t = tmp[i]; tmp[i] = tmp[j]; tmp[j] = t;
      }
      int sel[64];
      for(int i=0;i<64;i++) sel[i]=tmp[i];
      std::sort(sel, sel+64);
      int* dstp = pass ? idx.kv : idx.q;
      for(int i=0;i<64;i++) dstp[i]=sel[i];
    }
  }

  fca_tables<<<dim3(1536),256,0,stream>>>(ws, idx);
  fca_wt    <<<dim3(8192),256,0,stream>>>(wr, wi, (float2*)(ws+OFF_WT));
  fca_dft   <<<dim3(32,4,2),256,0,stream>>>(q, k, ws);
  fca_scores<<<dim3(32,8),256,0,stream>>>(ws);
  fca_pv    <<<dim3(32,8),256,0,stream>>>(ws);
  fca_ow    <<<dim3(8,64),256,0,stream>>>(ws);
  fca_irfft <<<dim3(32,8,8),256,0,stream>>>(ws, out);
}

// Round 4
// 1174.721 us; speedup vs baseline: 1.5727x; 1.5727x over previous
//
#include <hip/hip_runtime.h>
#include <algorithm>
#include <stdint.h>

// Problem constants (fixed by reference)
#define NB 32
#define NH 8
#define NE 64
#define NO 64
#define NM 64
#define NL 2048

struct Idx128 { int q[64]; int kv[64]; };

// ---- workspace layout (float offsets) ----
#define OFF_FQ    0          // [t][m] float2      : 131072 float2
#define OFF_FKV   262144     // [t][m] float2
#define OFF_BAS   524288     // [p][m][l] float    : 2*64*2048
#define OFF_WT    786432     // [h][x][e][o] float2: 2097152 float2
#define OFF_XQ    4980736    // [b][h][m][e] float2
#define OFF_XK    7077888    // [b][h][m][e] float2
#define OFF_SC    9175040    // [b][h][x][y] float2
#define OFF_XQKV  11272192   // [h][x][b][e] float2
#define OFF_XW    13369344   // [b][h][m][p][o] float
// total 15,466,496 floats = 61.9 MB

// ============ host-side replication of numpy legacy RNG ============
namespace fca_mt {
struct MT {
  uint32_t mt[624]; int mti;
  void seed(uint32_t s){
    mt[0]=s;
    for(int i=1;i<624;i++) mt[i]=1812433253u*(mt[i-1]^(mt[i-1]>>30))+(uint32_t)i;
    mti=624;
  }
  uint32_t next(){
    if(mti>=624){
      for(int i=0;i<624;i++){
        uint32_t y=(mt[i]&0x80000000u)|(mt[(i+1)%624]&0x7fffffffu);
        uint32_t v=mt[(i+397)%624]^(y>>1);
        if(y&1u) v^=0x9908b0dfu;
        mt[i]=v;
      }
      mti=0;
    }
    uint32_t y=mt[mti++];
    y^=y>>11; y^=(y<<7)&0x9d2c5680u; y^=(y<<15)&0xefc60000u; y^=y>>18;
    return y;
  }
  uint32_t interval(uint32_t mx){   // numpy random_interval: masked rejection
    if(mx==0) return 0;
    uint32_t mask=mx;
    mask|=mask>>1; mask|=mask>>2; mask|=mask>>4; mask|=mask>>8; mask|=mask>>16;
    uint32_t v;
    do { v = next()&mask; } while(v>mx);
    return v;
  }
};
} // namespace

// ============ table generation ============
// Angles are integer-reduced mod 2048 BEFORE the trig call, so fp32 sincosf
// (arg < 2*pi, fast path) is as accurate as fp64 was. Scale 2^-29 is exact.
__global__ __launch_bounds__(256) void fca_tables(float* __restrict__ ws, Idx128 idx){
  int i = blockIdx.x*256 + threadIdx.x;
  const float W = 0.00306796157577128f;   // 2*pi/2048 (fp32)
  if(i < 131072){                       // FQ[t][m] = e^{-2pi i f t / L}
    int t = i>>6, m = i&63;
    int f = idx.q[m];
    int r = (f*t) & 2047;
    float s, c; sincosf((float)r * W, &s, &c);
    ((float2*)(ws+OFF_FQ))[i] = make_float2(c, -s);
  } else if(i < 262144){                // FKV[t][m]
    int j = i-131072;
    int t = j>>6, m = j&63;
    int f = idx.kv[m];
    int r = (f*t) & 2047;
    float s, c; sincosf((float)r * W, &s, &c);
    ((float2*)(ws+OFF_FKV))[j] = make_float2(c, -s);
  } else if(i < 393216){                // BAS: BC[m][l], BS[m][l]
    int j = i-262144;
    int m = j>>11, l = j&2047;
    int f = idx.q[m];
    int r = (f*l) & 2047;
    float s, c; sincosf((float)r * W, &s, &c);
    float a = ((f==0)?1.0f:2.0f) * 0x1p-29f;  // 1/(2048*262144), exact pow2
    float* bas = ws+OFF_BAS;
    bas[j]          =  a*c;
    bas[131072 + j] = -a*s;
  }
}

// transpose weights: w[h][e][o][x] -> wt[h][x][e][o]; output-indexed so the
// float2 WRITES are coalesced (reads hit L2/L3).
__global__ __launch_bounds__(256) void fca_wt(const float* __restrict__ wr, const float* __restrict__ wi,
                                              float2* __restrict__ wt){
  int i = blockIdx.x*256 + threadIdx.x;   // < 2097152, output index
  int o = i&63, e = (i>>6)&63, x = (i>>12)&63, h = i>>18;
  int s = ((h*64+e)*64+o)*64 + x;
  wt[i] = make_float2(wr[s], wi[s]);
}

// sparse-mode DFT over t (K=2048): X[b][h][m][e] for q (z=0) and k (z=1).
// 1024-thread blocks; lane bits 4-5 select one of 4 t-subranges (512 t each);
// final shfl_xor(16/32) butterfly sums the subranges. 16 waves/CU.
__global__ __launch_bounds__(1024,4) void fca_dft(const float* __restrict__ qg, const float* __restrict__ kg,
                                                  float* __restrict__ ws){
  const int b   = blockIdx.x;   // 32
  const int heq = blockIdx.y;   // 4 : he-quarter (128 channels)
  const int isK = blockIdx.z;   // 2
  const float* src = isK ? kg : qg;
  const float2* tab = (const float2*)(ws + (isK ? OFF_FKV : OFF_FQ));
  float2* dst = (float2*)(ws + (isK ? OFF_XK : OFF_XQ));

  __shared__ float  lq[4][8][128];   // [tsub][tt][he]  16 KiB
  __shared__ float2 lt[4][8][65];    // [tsub][tt][m]+pad  16.6 KiB

  const int tid  = threadIdx.x;
  const int lane = tid & 63;
  const int wv   = tid >> 6;         // wave id 0..15
  const int tsub = lane >> 4;        // t-subrange 0..3 (in-wave)
  const int l4   = lane & 15;
  const int ot   = wv*16 + l4;       // output-thread id 0..255
  const int he0  = (ot & 31) * 4;    // 4 consecutive channels
  const int m0   = (ot >> 5) * 8;    // 8 modes

  // staging decomposition (1024 threads)
  const int sw  = tid >> 8;          // 0..3  (tsub window)
  const int stt = (tid >> 5) & 7;    // 0..7  (row in window)
  const int sc  = tid & 31;          // 0..31

  float accr[4][8], acci[4][8];
  #pragma unroll
  for(int j=0;j<4;j++){
    #pragma unroll
    for(int mm=0;mm<8;mm++){ accr[j][mm]=0.f; acci[j][mm]=0.f; }
  }

  for(int s=0;s<64;s++){
    {
      const int t = sw*512 + s*8 + stt;
      const float4 qv4 = *(const float4*)&src[ ((size_t)(b*2048 + t))*512 + heq*128 + sc*4 ];
      *(float4*)&lq[sw][stt][sc*4] = qv4;
      const float4 tv4 = *(const float4*)&tab[ t*64 + sc*2 ];
      lt[sw][stt][sc*2]   = make_float2(tv4.x, tv4.y);
      lt[sw][stt][sc*2+1] = make_float2(tv4.z, tv4.w);
    }
    __syncthreads();
    #pragma unroll
    for(int tt=0;tt<8;tt++){
      const float4 qa = *(const float4*)&lq[tsub][tt][he0];
      #pragma unroll
      for(int mm=0;mm<8;mm++){
        const float2 f = lt[tsub][tt][m0+mm];
        accr[0][mm] += qa.x*f.x; acci[0][mm] += qa.x*f.y;
        accr[1][mm] += qa.y*f.x; acci[1][mm] += qa.y*f.y;
        accr[2][mm] += qa.z*f.x; acci[2][mm] += qa.z*f.y;
        accr[3][mm] += qa.w*f.x; acci[3][mm] += qa.w*f.y;
      }
    }
    __syncthreads();
  }

  // butterfly-sum the 4 t-subranges (lane bits 4 and 5), then tsub==0 writes
  #pragma unroll
  for(int j=0;j<4;j++){
    #pragma unroll
    for(int mm=0;mm<8;mm++){
      float r  = accr[j][mm], im = acci[j][mm];
      r  += __shfl_xor(r, 16);  r  += __shfl_xor(r, 32);
      im += __shfl_xor(im, 16); im += __shfl_xor(im, 32);
      if(tsub == 0){
        const int he = heq*128 + he0 + j;
        dst[ ((size_t)((b*8 + (he>>6))*64 + (m0+mm)))*64 + (he&63) ] = make_float2(r, im);
      }
    }
  }
}

// complex tanh. For |x| >= ~11.1, tanhf(x) rounds to exactly +-1.0f so the
// full formula collapses to (+-1, 0): take that fast path (bit-identical)
// and skip tanf's Payne-Hanek slow path for 99.9% of the huge-|x| scores.
__device__ __forceinline__ float2 fca_ctanh(float2 z){
  if(fabsf(z.x) > 12.0f) return make_float2(copysignf(1.0f, z.x), 0.0f);
  float tx = tanhf(z.x);
  float ty = tanf(z.y);
  float tx2 = tx*tx, ty2 = ty*ty;
  float d = 1.0f + tx2*ty2;
  return make_float2( tx*(1.0f+ty2)/d, ty*(1.0f-tx2)/d );
}

// scores[b][h][x][y] = tanh( sum_e xq[x][e]*xk[y][e] )   (complex, no conj)
__global__ __launch_bounds__(256) void fca_scores(float* __restrict__ ws){
  const int b = blockIdx.x, h = blockIdx.y, xg0 = blockIdx.z*16;
  __shared__ float2 lxq[16][64];   // [x][e]
  __shared__ float2 lxk[64][65];   // [e][y] transposed, padded
  const int tid = threadIdx.x;
  const float2* srcq = (const float2*)(ws+OFF_XQ) + (size_t)(b*8+h)*4096;
  const float2* srck = (const float2*)(ws+OFF_XK) + (size_t)(b*8+h)*4096;
  #pragma unroll
  for(int kk=0;kk<4;kk++){
    int el = kk*256 + tid;
    int x = el>>6, e = el&63;
    lxq[x][e] = srcq[(xg0+x)*64 + e];
  }
  #pragma unroll
  for(int kk=0;kk<16;kk++){
    int el = kk*256 + tid;
    int y = el>>6, e = el&63;
    lxk[e][y] = srck[el];
  }
  __syncthreads();
  const int y = tid&63, xi = tid>>6;
  float2 acc[4];
  #pragma unroll
  for(int i=0;i<4;i++) acc[i]=make_float2(0.f,0.f);
  for(int e=0;e<64;e++){
    const float2 kv = lxk[e][y];
    #pragma unroll
    for(int i=0;i<4;i++){
      const float2 qv = lxq[xi*4+i][e];
      acc[i].x += qv.x*kv.x - qv.y*kv.y;
      acc[i].y += qv.x*kv.y + qv.y*kv.x;
    }
  }
  float2* outp = (float2*)(ws+OFF_SC) + (size_t)(b*8+h)*4096;
  #pragma unroll
  for(int i=0;i<4;i++){
    outp[(xg0+xi*4+i)*64 + y] = fca_ctanh(acc[i]);
  }
}

// xqkv[h][x][b][e] = sum_y scores[x][y] * xk[y][e]
__global__ __launch_bounds__(256) void fca_pv(float* __restrict__ ws){
  const int b = blockIdx.x, h = blockIdx.y, xg0 = blockIdx.z*16;
  __shared__ float2 ls[16][64];   // [x][y]
  __shared__ float2 lk[64][64];   // [y][e]
  const int tid = threadIdx.x;
  const float2* srcs = (const float2*)(ws+OFF_SC) + (size_t)(b*8+h)*4096;
  const float2* srck = (const float2*)(ws+OFF_XK) + (size_t)(b*8+h)*4096;
  #pragma unroll
  for(int kk=0;kk<4;kk++){
    int el = kk*256 + tid;
    int x = el>>6, y = el&63;
    ls[x][y] = srcs[(xg0+x)*64 + y];
  }
  #pragma unroll
  for(int kk=0;kk<16;kk++){
    int el = kk*256 + tid;
    ((float2*)lk)[el] = srck[el];
  }
  __syncthreads();
  const int e = tid&63, xi = tid>>6;
  float2 acc[4];
  #pragma unroll
  for(int i=0;i<4;i++) acc[i]=make_float2(0.f,0.f);
  for(int y=0;y<64;y++){
    const float2 kv = lk[y][e];
    #pragma unroll
    for(int i=0;i<4;i++){
      const float2 s = ls[xi*4+i][y];
      acc[i].x += s.x*kv.x - s.y*kv.y;
      acc[i].y += s.x*kv.y + s.y*kv.x;
    }
  }
  float2* dst = (float2*)(ws+OFF_XQKV);
  #pragma unroll
  for(int i=0;i<4;i++){
    int x = xg0 + xi*4 + i;
    dst[ ((size_t)(h*64+x)*32 + b)*64 + e ] = acc[i];
  }
}

// xw[b][h][x][p][o] = sum_e xqkv[h][x][b][e] * wt[h][x][e][o]
__global__ __launch_bounds__(256) void fca_ow(float* __restrict__ ws){
  const int h = blockIdx.x, x = blockIdx.y, bh0 = blockIdx.z*16;
  __shared__ float2 lw[64][64];  // [e][o]
  __shared__ float2 lx[16][64];  // [b][e]
  const int tid = threadIdx.x;
  const float2* srcw = (const float2*)(ws+OFF_WT)   + (size_t)(h*64+x)*4096;
  const float2* srcx = (const float2*)(ws+OFF_XQKV) + (size_t)(h*64+x)*2048;
  #pragma unroll
  for(int kk=0;kk<16;kk++){ int el=kk*256+tid; ((float2*)lw)[el]=srcw[el]; }
  #pragma unroll
  for(int kk=0;kk<4;kk++){
    int el = kk*256 + tid;
    int bl = el>>6, e = el&63;
    lx[bl][e] = srcx[(bh0+bl)*64 + e];
  }
  __syncthreads();
  const int o = tid&63, bg = tid>>6;
  float2 acc[4];
  #pragma unroll
  for(int i=0;i<4;i++) acc[i]=make_float2(0.f,0.f);
  for(int e=0;e<64;e++){
    const float2 wv = lw[e][o];
    #pragma unroll
    for(int i=0;i<4;i++){
      const float2 xv = lx[bg*4+i][e];
      acc[i].x += xv.x*wv.x - xv.y*wv.y;
      acc[i].y += xv.x*wv.y + xv.y*wv.x;
    }
  }
  float* xw = ws+OFF_XW;
  #pragma unroll
  for(int i=0;i<4;i++){
    int bb = bh0 + bg*4 + i;
    size_t base = ((size_t)((bb*8+h)*64 + x))*128;
    xw[base + o]      = acc[i].x;
    xw[base + 64 + o] = acc[i].y;
  }
}

// out[b][h][o][l] = sum_m ReX[m][o]*BC[m][l] + ImX[m][o]*BS[m][l]
// o split in halves, basis staged 8 modes at a time -> 32 KiB LDS, grid 4096.
__global__ __launch_bounds__(256) void fca_irfft(const float* __restrict__ ws, float* __restrict__ outg){
  const int b = blockIdx.x, h = blockIdx.y;
  const int oh = blockIdx.z & 1, lc = blockIdx.z >> 1;  // o-half, l-chunk of 256
  __shared__ float lX[64][2][32];    // [m][re/im][o-local] 16 KiB
  __shared__ float lB[8][2][256];    // [m][cos/sin][l]     16 KiB
  const int tid = threadIdx.x;
  const float* xw = ws+OFF_XW + (size_t)(b*8+h)*8192;
  // Stage ALL 64 modes x 2 planes x 32 o = 4096 floats as 1024 float4.
  // (Round-2 bug: scalar kk<8 staged only half of lX -> uninit LDS reads.)
  #pragma unroll
  for(int kk=0;kk<4;kk++){
    int el = kk*256 + tid;             // < 1024 float4
    int m = el>>4, p = (el>>3)&1, o4 = el&7;
    ((float4*)lX)[el] = *(const float4*)&xw[m*128 + p*64 + oh*32 + o4*4];
  }
  const int li = tid&63, og = tid>>6;
  float4 acc[8];
  #pragma unroll
  for(int a=0;a<8;a++) acc[a]=make_float4(0.f,0.f,0.f,0.f);
  const float* bas = ws+OFF_BAS;
  for(int mc=0;mc<8;mc++){
    __syncthreads();
    #pragma unroll
    for(int kk=0;kk<16;kk++){
      int el = kk*256+tid;               // < 4096 floats = full lB
      int m = el>>9, p = (el>>8)&1, l = el&255;
      lB[m][p][l] = bas[p*131072 + (mc*8+m)*2048 + lc*256 + l];
    }
    __syncthreads();
    #pragma unroll
    for(int m=0;m<8;m++){
      const int gm = mc*8+m;
      const float4 bc = *(const float4*)&lB[m][0][li*4];
      const float4 bs = *(const float4*)&lB[m][1][li*4];
      #pragma unroll
      for(int i2=0;i2<2;i2++){
        const float4 xr = *(const float4*)&lX[gm][0][og*8+i2*4];
        const float4 xi = *(const float4*)&lX[gm][1][og*8+i2*4];
        const float xrv[4] = {xr.x, xr.y, xr.z, xr.w};
        const float xiv[4] = {xi.x, xi.y, xi.z, xi.w};
        #pragma unroll
        for(int c=0;c<4;c++){
          float4& A = acc[i2*4+c];
          A.x += xrv[c]*bc.x + xiv[c]*bs.x;
          A.y += xrv[c]*bc.y + xiv[c]*bs.y;
          A.z += xrv[c]*bc.z + xiv[c]*bs.z;
          A.w += xrv[c]*bc.w + xiv[c]*bs.w;
        }
      }
    }
  }
  #pragma unroll
  for(int a=0;a<8;a++){
    int o = oh*32 + og*8 + a;
    *(float4*)&outg[ ((size_t)((b*8+h)*64 + o))*2048 + lc*256 + li*4 ] = acc[a];
  }
}

extern "C" void kernel_launch(void* const* d_in, const int* in_sizes, int n_in,
                              void* d_out, int out_size, void* d_ws, size_t ws_size,
                              hipStream_t stream) {
  (void)in_sizes; (void)n_in; (void)out_size; (void)ws_size;
  const float* q  = (const float*)d_in[0];
  const float* k  = (const float*)d_in[1];
  const float* wr = (const float*)d_in[4];
  const float* wi = (const float*)d_in[5];
  float* out = (float*)d_out;
  float* ws  = (float*)d_ws;

  // Replicate the reference's module-level mode selection exactly
  // (np.random.seed(0); shuffle(arange(1024)) twice, first 64 sorted each).
  Idx128 idx;
  {
    fca_mt::MT rng; rng.seed(0u);
    int tmp[1024];
    for(int pass=0; pass<2; pass++){
      for(int i=0;i<1024;i++) tmp[i]=i;
      for(int i=1023;i>0;i--){
        int j = (int)rng.interval((uint32_t)i);
        int t = tmp[i]; tmp[i] = tmp[j]; tmp[j] = t;
      }
      int sel[64];
      for(int i=0;i<64;i++) sel[i]=tmp[i];
      std::sort(sel, sel+64);
      int* dstp = pass ? idx.kv : idx.q;
      for(int i=0;i<64;i++) dstp[i]=sel[i];
    }
  }

  fca_tables<<<dim3(1536),256,0,stream>>>(ws, idx);
  fca_wt    <<<dim3(8192),256,0,stream>>>(wr, wi, (float2*)(ws+OFF_WT));
  fca_dft   <<<dim3(32,4,2),1024,0,stream>>>(q, k, ws);
  fca_scores<<<dim3(32,8,4),256,0,stream>>>(ws);
  fca_pv    <<<dim3(32,8,4),256,0,stream>>>(ws);
  fca_ow    <<<dim3(8,64,2),256,0,stream>>>(ws);
  fca_irfft <<<dim3(32,8,16),256,0,stream>>>(ws, out);
}

// Round 7
// 769.179 us; speedup vs baseline: 2.4019x; 1.5272x over previous
//
#include <hip/hip_runtime.h>
#include <algorithm>
#include <stdint.h>

// Problem constants (fixed by reference)
#define NB 32
#define NH 8
#define NE 64
#define NO 64
#define NM 64
#define NL 2048

struct Idx128 { int q[64]; int kv[64]; };

// ---- workspace layout (float offsets) ----
#define OFF_FQ    0          // [t][m] float2      : 131072 float2
#define OFF_FKV   262144     // [t][m] float2
#define OFF_BAS   524288     // [k][l] float, k=m*2+p : 128*2048
#define OFF_WT    786432     // [h][x][e][o] float2: 2097152 float2
#define OFF_XQ    4980736    // [b][h][m][e] float2
#define OFF_XK    7077888    // [b][h][m][e] float2
#define OFF_SC    9175040    // [b][h][x][y] float2
#define OFF_XQKV  11272192   // [h][x][b][e] float2
#define OFF_XW    13369344   // [b][h][m][p][o] float  (= [bh][k][o], k=m*2+p)
// total 15,466,496 floats = 61.9 MB

// ============ host-side replication of numpy legacy RNG ============
namespace fca_mt {
struct MT {
  uint32_t mt[624]; int mti;
  void seed(uint32_t s){
    mt[0]=s;
    for(int i=1;i<624;i++) mt[i]=1812433253u*(mt[i-1]^(mt[i-1]>>30))+(uint32_t)i;
    mti=624;
  }
  uint32_t next(){
    if(mti>=624){
      for(int i=0;i<624;i++){
        uint32_t y=(mt[i]&0x80000000u)|(mt[(i+1)%624]&0x7fffffffu);
        uint32_t v=mt[(i+397)%624]^(y>>1);
        if(y&1u) v^=0x9908b0dfu;
        mt[i]=v;
      }
      mti=0;
    }
    uint32_t y=mt[mti++];
    y^=y>>11; y^=(y<<7)&0x9d2c5680u; y^=(y<<15)&0xefc60000u; y^=y>>18;
    return y;
  }
  uint32_t interval(uint32_t mx){   // numpy random_interval: masked rejection
    if(mx==0) return 0;
    uint32_t mask=mx;
    mask|=mask>>1; mask|=mask>>2; mask|=mask>>4; mask|=mask>>8; mask|=mask>>16;
    uint32_t v;
    do { v = next()&mask; } while(v>mx);
    return v;
  }
};
} // namespace

// ============ table generation ============
// Angles are integer-reduced mod 2048 BEFORE the trig call, so fp32 sincosf
// (arg < 2*pi, fast path) is as accurate as fp64 was. Scale 2^-29 is exact.
__global__ __launch_bounds__(256) void fca_tables(float* __restrict__ ws, Idx128 idx){
  int i = blockIdx.x*256 + threadIdx.x;
  const float W = 0.00306796157577128f;   // 2*pi/2048 (fp32)
  if(i < 131072){                       // FQ[t][m] = e^{-2pi i f t / L}
    int t = i>>6, m = i&63;
    int f = idx.q[m];
    int r = (f*t) & 2047;
    float s, c; sincosf((float)r * W, &s, &c);
    ((float2*)(ws+OFF_FQ))[i] = make_float2(c, -s);
  } else if(i < 262144){                // FKV[t][m]
    int j = i-131072;
    int t = j>>6, m = j&63;
    int f = idx.kv[m];
    int r = (f*t) & 2047;
    float s, c; sincosf((float)r * W, &s, &c);
    ((float2*)(ws+OFF_FKV))[j] = make_float2(c, -s);
  } else if(i < 393216){                // BAS2[k][l], k=m*2+p (cos plane, sin plane interleaved)
    int j = i-262144;                   // < 131072
    int m = j>>11, l = j&2047;
    int f = idx.q[m];
    int r = (f*l) & 2047;
    float s, c; sincosf((float)r * W, &s, &c);
    float a = ((f==0)?1.0f:2.0f) * 0x1p-29f;  // 1/(2048*262144), exact pow2
    float* bas = ws+OFF_BAS;
    bas[(m*2+0)*2048 + l] =  a*c;
    bas[(m*2+1)*2048 + l] = -a*s;
  }
}

// transpose weights: w[h][e][o][x] -> wt[h][x][e][o]; output-indexed so the
// float2 WRITES are coalesced (reads hit L2/L3).
__global__ __launch_bounds__(256) void fca_wt(const float* __restrict__ wr, const float* __restrict__ wi,
                                              float2* __restrict__ wt){
  int i = blockIdx.x*256 + threadIdx.x;   // < 2097152, output index
  int o = i&63, e = (i>>6)&63, x = (i>>12)&63, h = i>>18;
  int s = ((h*64+e)*64+o)*64 + x;
  wt[i] = make_float2(wr[s], wi[s]);
}

// sparse-mode DFT over t (K=2048): X[b][h][m][e] for q (z=0) and k (z=1).
// 1024-thread blocks; lane bits 4-5 select one of 4 t-subranges (512 t each);
// final shfl_xor(16/32) butterfly sums the subranges. 16 waves/CU.
__global__ __launch_bounds__(1024,4) void fca_dft(const float* __restrict__ qg, const float* __restrict__ kg,
                                                  float* __restrict__ ws){
  const int b   = blockIdx.x;   // 32
  const int heq = blockIdx.y;   // 4 : he-quarter (128 channels)
  const int isK = blockIdx.z;   // 2
  const float* src = isK ? kg : qg;
  const float2* tab = (const float2*)(ws + (isK ? OFF_FKV : OFF_FQ));
  float2* dst = (float2*)(ws + (isK ? OFF_XK : OFF_XQ));

  __shared__ float  lq[4][8][128];   // [tsub][tt][he]  16 KiB
  __shared__ float2 lt[4][8][65];    // [tsub][tt][m]+pad  16.6 KiB

  const int tid  = threadIdx.x;
  const int lane = tid & 63;
  const int wv   = tid >> 6;         // wave id 0..15
  const int tsub = lane >> 4;        // t-subrange 0..3 (in-wave)
  const int l4   = lane & 15;
  const int ot   = wv*16 + l4;       // output-thread id 0..255
  const int he0  = (ot & 31) * 4;    // 4 consecutive channels
  const int m0   = (ot >> 5) * 8;    // 8 modes

  // staging decomposition (1024 threads)
  const int sw  = tid >> 8;          // 0..3  (tsub window)
  const int stt = (tid >> 5) & 7;    // 0..7  (row in window)
  const int sc  = tid & 31;          // 0..31

  float accr[4][8], acci[4][8];
  #pragma unroll
  for(int j=0;j<4;j++){
    #pragma unroll
    for(int mm=0;mm<8;mm++){ accr[j][mm]=0.f; acci[j][mm]=0.f; }
  }

  for(int s=0;s<64;s++){
    {
      const int t = sw*512 + s*8 + stt;
      const float4 qv4 = *(const float4*)&src[ ((size_t)(b*2048 + t))*512 + heq*128 + sc*4 ];
      *(float4*)&lq[sw][stt][sc*4] = qv4;
      const float4 tv4 = *(const float4*)&tab[ t*64 + sc*2 ];
      lt[sw][stt][sc*2]   = make_float2(tv4.x, tv4.y);
      lt[sw][stt][sc*2+1] = make_float2(tv4.z, tv4.w);
    }
    __syncthreads();
    #pragma unroll
    for(int tt=0;tt<8;tt++){
      const float4 qa = *(const float4*)&lq[tsub][tt][he0];
      #pragma unroll
      for(int mm=0;mm<8;mm++){
        const float2 f = lt[tsub][tt][m0+mm];
        accr[0][mm] += qa.x*f.x; acci[0][mm] += qa.x*f.y;
        accr[1][mm] += qa.y*f.x; acci[1][mm] += qa.y*f.y;
        accr[2][mm] += qa.z*f.x; acci[2][mm] += qa.z*f.y;
        accr[3][mm] += qa.w*f.x; acci[3][mm] += qa.w*f.y;
      }
    }
    __syncthreads();
  }

  // butterfly-sum the 4 t-subranges (lane bits 4 and 5), then tsub==0 writes
  #pragma unroll
  for(int j=0;j<4;j++){
    #pragma unroll
    for(int mm=0;mm<8;mm++){
      float r  = accr[j][mm], im = acci[j][mm];
      r  += __shfl_xor(r, 16);  r  += __shfl_xor(r, 32);
      im += __shfl_xor(im, 16); im += __shfl_xor(im, 32);
      if(tsub == 0){
        const int he = heq*128 + he0 + j;
        dst[ ((size_t)((b*8 + (he>>6))*64 + (m0+mm)))*64 + (he&63) ] = make_float2(r, im);
      }
    }
  }
}

// complex tanh. For |x| >= ~11.1, tanhf(x) rounds to exactly +-1.0f so the
// full formula collapses to (+-1, 0): take that fast path (bit-identical)
// and skip tanf's Payne-Hanek slow path for 99.9% of the huge-|x| scores.
__device__ __forceinline__ float2 fca_ctanh(float2 z){
  if(fabsf(z.x) > 12.0f) return make_float2(copysignf(1.0f, z.x), 0.0f);
  float tx = tanhf(z.x);
  float ty = tanf(z.y);
  float tx2 = tx*tx, ty2 = ty*ty;
  float d = 1.0f + tx2*ty2;
  return make_float2( tx*(1.0f+ty2)/d, ty*(1.0f-tx2)/d );
}

// scores[b][h][x][y] = tanh( sum_e xq[x][e]*xk[y][e] )   (complex, no conj)
__global__ __launch_bounds__(256) void fca_scores(float* __restrict__ ws){
  const int b = blockIdx.x, h = blockIdx.y, xg0 = blockIdx.z*16;
  __shared__ float2 lxq[16][64];   // [x][e]
  __shared__ float2 lxk[64][65];   // [e][y] transposed, padded
  const int tid = threadIdx.x;
  const float2* srcq = (const float2*)(ws+OFF_XQ) + (size_t)(b*8+h)*4096;
  const float2* srck = (const float2*)(ws+OFF_XK) + (size_t)(b*8+h)*4096;
  #pragma unroll
  for(int kk=0;kk<4;kk++){
    int el = kk*256 + tid;
    int x = el>>6, e = el&63;
    lxq[x][e] = srcq[(xg0+x)*64 + e];
  }
  #pragma unroll
  for(int kk=0;kk<16;kk++){
    int el = kk*256 + tid;
    int y = el>>6, e = el&63;
    lxk[e][y] = srck[el];
  }
  __syncthreads();
  const int y = tid&63, xi = tid>>6;
  float2 acc[4];
  #pragma unroll
  for(int i=0;i<4;i++) acc[i]=make_float2(0.f,0.f);
  for(int e=0;e<64;e++){
    const float2 kv = lxk[e][y];
    #pragma unroll
    for(int i=0;i<4;i++){
      const float2 qv = lxq[xi*4+i][e];
      acc[i].x += qv.x*kv.x - qv.y*kv.y;
      acc[i].y += qv.x*kv.y + qv.y*kv.x;
    }
  }
  float2* outp = (float2*)(ws+OFF_SC) + (size_t)(b*8+h)*4096;
  #pragma unroll
  for(int i=0;i<4;i++){
    outp[(xg0+xi*4+i)*64 + y] = fca_ctanh(acc[i]);
  }
}

// xqkv[h][x][b][e] = sum_y scores[x][y] * xk[y][e]
__global__ __launch_bounds__(256) void fca_pv(float* __restrict__ ws){
  const int b = blockIdx.x, h = blockIdx.y, xg0 = blockIdx.z*16;
  __shared__ float2 ls[16][64];   // [x][y]
  __shared__ float2 lk[64][64];   // [y][e]
  const int tid = threadIdx.x;
  const float2* srcs = (const float2*)(ws+OFF_SC) + (size_t)(b*8+h)*4096;
  const float2* srck = (const float2*)(ws+OFF_XK) + (size_t)(b*8+h)*4096;
  #pragma unroll
  for(int kk=0;kk<4;kk++){
    int el = kk*256 + tid;
    int x = el>>6, y = el&63;
    ls[x][y] = srcs[(xg0+x)*64 + y];
  }
  #pragma unroll
  for(int kk=0;kk<16;kk++){
    int el = kk*256 + tid;
    ((float2*)lk)[el] = srck[el];
  }
  __syncthreads();
  const int e = tid&63, xi = tid>>6;
  float2 acc[4];
  #pragma unroll
  for(int i=0;i<4;i++) acc[i]=make_float2(0.f,0.f);
  for(int y=0;y<64;y++){
    const float2 kv = lk[y][e];
    #pragma unroll
    for(int i=0;i<4;i++){
      const float2 s = ls[xi*4+i][y];
      acc[i].x += s.x*kv.x - s.y*kv.y;
      acc[i].y += s.x*kv.y + s.y*kv.x;
    }
  }
  float2* dst = (float2*)(ws+OFF_XQKV);
  #pragma unroll
  for(int i=0;i<4;i++){
    int x = xg0 + xi*4 + i;
    dst[ ((size_t)(h*64+x)*32 + b)*64 + e ] = acc[i];
  }
}

// xw[b][h][x][p][o] = sum_e xqkv[h][x][b][e] * wt[h][x][e][o]
__global__ __launch_bounds__(256) void fca_ow(float* __restrict__ ws){
  const int h = blockIdx.x, x = blockIdx.y, bh0 = blockIdx.z*16;
  __shared__ float2 lw[64][64];  // [e][o]
  __shared__ float2 lx[16][64];  // [b][e]
  const int tid = threadIdx.x;
  const float2* srcw = (const float2*)(ws+OFF_WT)   + (size_t)(h*64+x)*4096;
  const float2* srcx = (const float2*)(ws+OFF_XQKV) + (size_t)(h*64+x)*2048;
  #pragma unroll
  for(int kk=0;kk<16;kk++){ int el=kk*256+tid; ((float2*)lw)[el]=srcw[el]; }
  #pragma unroll
  for(int kk=0;kk<4;kk++){
    int el = kk*256 + tid;
    int bl = el>>6, e = el&63;
    lx[bl][e] = srcx[(bh0+bl)*64 + e];
  }
  __syncthreads();
  const int o = tid&63, bg = tid>>6;
  float2 acc[4];
  #pragma unroll
  for(int i=0;i<4;i++) acc[i]=make_float2(0.f,0.f);
  for(int e=0;e<64;e++){
    const float2 wv = lw[e][o];
    #pragma unroll
    for(int i=0;i<4;i++){
      const float2 xv = lx[bg*4+i][e];
      acc[i].x += xv.x*wv.x - xv.y*wv.y;
      acc[i].y += xv.x*wv.y + xv.y*wv.x;
    }
  }
  float* xw = ws+OFF_XW;
  #pragma unroll
  for(int i=0;i<4;i++){
    int bb = bh0 + bg*4 + i;
    size_t base = ((size_t)((bb*8+h)*64 + x))*128;
    xw[base + o]      = acc[i].x;
    xw[base + 64 + o] = acc[i].y;
  }
}

// out[bh][o][l] = sum_k XW[bh][k][o] * BAS2[k][l], K=128 (k = m*2 + re/im).
// Barrier-free K-loop: XW staged to LDS once; basis streamed as coalesced
// global float4 (L2-resident); X read as wave-uniform LDS broadcasts.
// 64 accumulators/thread; no __syncthreads after the single stage barrier.
__global__ __launch_bounds__(256,4) void fca_irfft(const float* __restrict__ ws, float* __restrict__ outg){
  const int bh = blockIdx.x;            // 256
  const int l0 = blockIdx.y * 256;      // 8 l-chunks
  __shared__ float lX[128][64];         // [k][o] 32 KiB
  const int tid = threadIdx.x;
  const float* xw = ws+OFF_XW + (size_t)bh*8192;
  // stage: 8192 floats = 2048 float4 (xw layout [m][p][o] == [k][o] flat)
  #pragma unroll
  for(int kk=0;kk<8;kk++){
    int el = kk*256 + tid;
    ((float4*)lX)[el] = ((const float4*)xw)[el];
  }
  __syncthreads();
  const int li = tid & 63;              // 4 l per lane
  const int w  = tid >> 6;              // wave -> o-group of 16
  const float* bas = ws + OFF_BAS + l0 + li*4;
  float4 acc[16];
  #pragma unroll
  for(int a=0;a<16;a++) acc[a]=make_float4(0.f,0.f,0.f,0.f);
  #pragma unroll 2
  for(int k=0;k<128;k++){
    const float4 bv = *(const float4*)&bas[k*2048];
    #pragma unroll
    for(int oi=0;oi<4;oi++){
      const float4 xv = *(const float4*)&lX[k][w*16 + oi*4];   // broadcast
      acc[oi*4+0].x += xv.x*bv.x; acc[oi*4+0].y += xv.x*bv.y; acc[oi*4+0].z += xv.x*bv.z; acc[oi*4+0].w += xv.x*bv.w;
      acc[oi*4+1].x += xv.y*bv.x; acc[oi*4+1].y += xv.y*bv.y; acc[oi*4+1].z += xv.y*bv.z; acc[oi*4+1].w += xv.y*bv.w;
      acc[oi*4+2].x += xv.z*bv.x; acc[oi*4+2].y += xv.z*bv.y; acc[oi*4+2].z += xv.z*bv.z; acc[oi*4+2].w += xv.z*bv.w;
      acc[oi*4+3].x += xv.w*bv.x; acc[oi*4+3].y += xv.w*bv.y; acc[oi*4+3].z += xv.w*bv.z; acc[oi*4+3].w += xv.w*bv.w;
    }
  }
  #pragma unroll
  for(int a=0;a<16;a++){
    int o = w*16 + a;
    *(float4*)&outg[ ((size_t)(bh*64 + o))*2048 + l0 + li*4 ] = acc[a];
  }
}

extern "C" void kernel_launch(void* const* d_in, const int* in_sizes, int n_in,
                              void* d_out, int out_size, void* d_ws, size_t ws_size,
                              hipStream_t stream) {
  (void)in_sizes; (void)n_in; (void)out_size; (void)ws_size;
  const float* q  = (const float*)d_in[0];
  const float* k  = (const float*)d_in[1];
  const float* wr = (const float*)d_in[4];
  const float* wi = (const float*)d_in[5];
  float* out = (float*)d_out;
  float* ws  = (float*)d_ws;

  // Replicate the reference's module-level mode selection exactly
  // (np.random.seed(0); shuffle(arange(1024)) twice, first 64 sorted each).
  Idx128 idx;
  {
    fca_mt::MT rng; rng.seed(0u);
    int tmp[1024];
    for(int pass=0; pass<2; pass++){
      for(int i=0;i<1024;i++) tmp[i]=i;
      for(int i=1023;i>0;i--){
        int j = (int)rng.interval((uint32_t)i);
        int t = tmp[i]; tmp[i] = tmp[j]; tmp[j] = t;
      }
      int sel[64];
      for(int i=0;i<64;i++) sel[i]=tmp[i];
      std::sort(sel, sel+64);
      int* dstp = pass ? idx.kv : idx.q;
      for(int i=0;i<64;i++) dstp[i]=sel[i];
    }
  }

  fca_tables<<<dim3(1536),256,0,stream>>>(ws, idx);
  fca_wt    <<<dim3(8192),256,0,stream>>>(wr, wi, (float2*)(ws+OFF_WT));
  fca_dft   <<<dim3(32,4,2),1024,0,stream>>>(q, k, ws);
  fca_scores<<<dim3(32,8,4),256,0,stream>>>(ws);
  fca_pv    <<<dim3(32,8,4),256,0,stream>>>(ws);
  fca_ow    <<<dim3(8,64,2),256,0,stream>>>(ws);
  fca_irfft <<<dim3(256,8),256,0,stream>>>(ws, out);
}